// Round 1
// baseline (161.441 us; speedup 1.0000x reference)
//
#include <hip/hip_runtime.h>
#include <math.h>

// D3 constants
#define K1C 16.0f
#define K2C (4.0f / 3.0f)
#define K3C 4.0f
#define A1C 0.4f
#define A2C 5.0f
#define S6C 1.0f
#define S8C 0.78f
#define CN_CUT 25.0f
#define DISP_CUT 50.0f
#define MAXZ 95
#define NREF 5

// ---------------- Kernel 1: coordination numbers (scatter-add) ----------------
__global__ void cn_kernel(const float* __restrict__ pos,
                          const int* __restrict__ numbers,
                          const int* __restrict__ ei,
                          const int* __restrict__ ej,
                          const float* __restrict__ rcov,
                          float* __restrict__ cn,
                          int n_edges) {
    int stride = gridDim.x * blockDim.x;
    for (int e = blockIdx.x * blockDim.x + threadIdx.x; e < n_edges; e += stride) {
        int i = ei[e];
        int j = ej[e];
        float dx = pos[3 * j + 0] - pos[3 * i + 0];
        float dy = pos[3 * j + 1] - pos[3 * i + 1];
        float dz = pos[3 * j + 2] - pos[3 * i + 2];
        float d = sqrtf(dx * dx + dy * dy + dz * dz + 1e-20f);
        if (d < CN_CUT) {
            int zi = numbers[i];
            int zj = numbers[j];
            float rr = rcov[zi] + rcov[zj];
            float x = K1C * (K2C * rr / d - 1.0f);
            float s = 1.0f / (1.0f + expf(-x));
            atomicAdd(&cn[i], s);
        }
    }
}

// ---------------- Kernel 2: per-atom CN-Gaussian weights ----------------
__global__ void weights_kernel(const float* __restrict__ cn,
                               const int* __restrict__ numbers,
                               const float* __restrict__ cn_ref,
                               float* __restrict__ W,
                               int n_atoms) {
    int stride = gridDim.x * blockDim.x;
    for (int a = blockIdx.x * blockDim.x + threadIdx.x; a < n_atoms; a += stride) {
        int z = numbers[a];
        float c = cn[a];
        float gw[NREF];
        float norm = 0.0f;
        float best = -INFINITY;
        int bi = 0;
#pragma unroll
        for (int m = 0; m < NREF; ++m) {
            float r = cn_ref[z * NREF + m];
            bool valid = (r >= 0.0f);
            float t = c - r;
            float g = valid ? expf(-K3C * t * t) : 0.0f;
            gw[m] = g;
            norm += g;
            if (valid && r > best) { best = r; bi = m; }  // first occurrence of max
        }
        if (norm > 1e-30f) {
            float inv = 1.0f / norm;
#pragma unroll
            for (int m = 0; m < NREF; ++m) W[a * NREF + m] = gw[m] * inv;
        } else {
#pragma unroll
            for (int m = 0; m < NREF; ++m) W[a * NREF + m] = (m == bi) ? 1.0f : 0.0f;
        }
    }
}

// ---------------- Kernel 3: pair dispersion energy + reduction ----------------
__global__ void energy_kernel(const float* __restrict__ pos,
                              const int* __restrict__ numbers,
                              const int* __restrict__ ei,
                              const int* __restrict__ ej,
                              const float* __restrict__ r4r2,
                              const float* __restrict__ c6tab,
                              const float* __restrict__ W,
                              double* __restrict__ acc,
                              int n_edges) {
    double local = 0.0;
    int stride = gridDim.x * blockDim.x;
    for (int e = blockIdx.x * blockDim.x + threadIdx.x; e < n_edges; e += stride) {
        int i = ei[e];
        int j = ej[e];
        float dx = pos[3 * j + 0] - pos[3 * i + 0];
        float dy = pos[3 * j + 1] - pos[3 * i + 1];
        float dz = pos[3 * j + 2] - pos[3 * i + 2];
        float d = sqrtf(dx * dx + dy * dy + dz * dz + 1e-20f);
        if (d < DISP_CUT) {
            int zi = numbers[i];
            int zj = numbers[j];
            const float* __restrict__ T = c6tab + ((size_t)(zi * MAXZ + zj)) * (NREF * NREF);
            float wi[NREF], wj[NREF];
#pragma unroll
            for (int m = 0; m < NREF; ++m) wi[m] = W[(size_t)i * NREF + m];
#pragma unroll
            for (int m = 0; m < NREF; ++m) wj[m] = W[(size_t)j * NREF + m];
            float c6 = 0.0f;
#pragma unroll
            for (int a = 0; a < NREF; ++a) {
                float s = 0.0f;
#pragma unroll
                for (int b = 0; b < NREF; ++b) s += wj[b] * T[a * NREF + b];
                c6 += wi[a] * s;
            }
            float qq = 3.0f * r4r2[zi] * r4r2[zj];
            float c8 = c6 * qq;
            float f = A1C * sqrtf(qq) + A2C;
            float f2 = f * f;
            float f6 = f2 * f2 * f2;
            float f8 = f6 * f2;
            float d2 = d * d;
            float d6 = d2 * d2 * d2;
            float d8 = d6 * d2;
            float e_pair = -(S6C * c6 / (d6 + f6) + S8C * c8 / (d8 + f8));
            local += 0.5 * (double)e_pair;
        }
    }
    // wave (64-lane) shuffle reduction
#pragma unroll
    for (int off = 32; off > 0; off >>= 1) local += __shfl_down(local, off, 64);
    __shared__ double wsum[8];  // up to 8 waves per block
    int lane = threadIdx.x & 63;
    int wave = threadIdx.x >> 6;
    if (lane == 0) wsum[wave] = local;
    __syncthreads();
    if (threadIdx.x == 0) {
        double b = 0.0;
        int nwaves = (blockDim.x + 63) >> 6;
        for (int w = 0; w < nwaves; ++w) b += wsum[w];
        atomicAdd(acc, b);
    }
}

// ---------------- Kernel 4: finalize ----------------
__global__ void finalize_kernel(const double* __restrict__ acc, float* __restrict__ out) {
    out[0] = (float)acc[0];
}

extern "C" void kernel_launch(void* const* d_in, const int* in_sizes, int n_in,
                              void* d_out, int out_size, void* d_ws, size_t ws_size,
                              hipStream_t stream) {
    const float* pos     = (const float*)d_in[0];
    const int*   numbers = (const int*)d_in[1];
    const int*   ei      = (const int*)d_in[2];
    const int*   ej      = (const int*)d_in[3];
    const float* rcov    = (const float*)d_in[4];
    const float* r4r2    = (const float*)d_in[5];
    const float* c6tab   = (const float*)d_in[6];
    const float* cn_ref  = (const float*)d_in[7];

    int n_atoms = in_sizes[1];
    int n_edges = in_sizes[2];

    char* ws = (char*)d_ws;
    size_t cn_bytes = (size_t)n_atoms * sizeof(float);
    size_t acc_off = (cn_bytes + 7) & ~(size_t)7;
    float*  cn  = (float*)ws;
    double* acc = (double*)(ws + acc_off);
    float*  W   = (float*)(ws + acc_off + sizeof(double));

    // zero cn[] and the double accumulator (W is fully overwritten)
    hipMemsetAsync(d_ws, 0, acc_off + sizeof(double), stream);

    const int block = 256;
    int egrid = (n_edges + block - 1) / block;
    if (egrid > 4096) egrid = 4096;
    int agrid = (n_atoms + block - 1) / block;

    cn_kernel<<<egrid, block, 0, stream>>>(pos, numbers, ei, ej, rcov, cn, n_edges);
    weights_kernel<<<agrid, block, 0, stream>>>(cn, numbers, cn_ref, W, n_atoms);
    energy_kernel<<<egrid, block, 0, stream>>>(pos, numbers, ei, ej, r4r2, c6tab, W, acc, n_edges);
    finalize_kernel<<<1, 1, 0, stream>>>(acc, (float*)d_out);
}